// Round 2
// baseline (8609.427 us; speedup 1.0000x reference)
//
#include <hip/hip_runtime.h>
#include <stdint.h>

// EISepLSTM: x(T,B,I) -> ig GEMM -> 512-step EI recurrence -> out GEMM.
// T=512, B=128, I=H=O=512.
// Round 2: recurrence is fully intra-CU. 8 blocks (one per 16-batch group),
// 256 threads (4 waves, 1/SIMD). Wrec (512 KB bf16) lives per-CU:
//   - 12 of 16 k-chunks in registers (96 short8/lane = 384 VGPR)
//   - 4  of 16 k-chunks in LDS (128 KB)
// a_t = h_t*ei_t exchanged across waves via 16 KB LDS tile + __syncthreads.
// No cross-block communication at all.

typedef __attribute__((ext_vector_type(8))) short short8;
typedef __attribute__((ext_vector_type(4))) float f32x4;

__device__ __forceinline__ unsigned short f2b(float f) {
  unsigned int u = __float_as_uint(f);
  u = (u + 0x7fffu + ((u >> 16) & 1u)) >> 16;   // RNE
  return (unsigned short)u;
}
__device__ __forceinline__ float b2f(unsigned short s) {
  return __uint_as_float(((unsigned int)s) << 16);
}

// ---------------- prep: ei2 (permuted), bf16 weight casts, c_last ----------
__global__ void prep_kernel(const float* __restrict__ gu,      // (T,H,2)
                            const float* __restrict__ logit,   // (H,2)
                            const float* __restrict__ wrec,    // (H,H)
                            const float* __restrict__ win,     // (H,I)
                            const float* __restrict__ wout,    // (O,H)
                            float* __restrict__ ei2,           // permuted
                            unsigned short* __restrict__ wrecb,
                            unsigned short* __restrict__ winb,
                            unsigned short* __restrict__ woutb,
                            float* __restrict__ c_last) {
  int i = blockIdx.x * 256 + threadIdx.x;          // 0 .. 262143
  int t = i >> 9, h = i & 511;
  float u0 = gu[2 * i], u1 = gu[2 * i + 1];
  float l0 = logit[2 * h], l1 = logit[2 * h + 1];
  float g0 = -logf(-logf(u0 + 1e-10f) + 1e-10f);
  float g1 = -logf(-logf(u1 + 1e-10f) + 1e-10f);
  // softmax2 diff == tanh(dz/2), dz = ((l0+g0)-(l1+g1))/tau
  float dz = ((l0 + g0) - (l1 + g1)) * 10.0f;
  float v = tanhf(0.5f * dz);
  // ei2[(t,w,l=lq*16+lm)][j] = ei[t][w*128+j*16+lm], replicated over lq
  int w = h >> 7, j = (h >> 4) & 7, lm = h & 15;
  size_t base = ((size_t)t * 4 + w) * 64;
#pragma unroll
  for (int lq = 0; lq < 4; ++lq)
    ei2[(base + lq * 16 + lm) * 8 + j] = v;
  wrecb[i] = f2b(fmaxf(wrec[i], 0.0f));
  winb[i]  = f2b(win[i]);
  woutb[i] = f2b(wout[i]);
  if (i < 65536) c_last[i] = 0.0f;
}

// ---------------- GEMM: C[m,n] = sum_k A[m,k]*W[n,k] + bias[n] -------------
// A: M x 512 (f32 or bf16), W: 512 x 512 bf16 row-major, out f32 or bf16.
// PERM: write bf16 out in the recurrence's lane-permuted ig layout.
template <int A_F32, int OUT_BF16, int PERM>
__global__ __launch_bounds__(256, 2) void gemm512(
    const void* __restrict__ Ap, const unsigned short* __restrict__ W,
    const float* __restrict__ bias, void* __restrict__ Cp) {
  __shared__ __align__(16) unsigned short Al[128][32];
  __shared__ __align__(16) unsigned short Bl[128][32];
  const int tid = threadIdx.x;
  const int w = tid >> 6, l = tid & 63;
  const int wr = w >> 1, wc = w & 1;
  const int lm = l & 15, lq = l >> 4;
  const size_t m0 = (size_t)blockIdx.x * 128;
  const int n0 = blockIdx.y * 128;
  const int r = tid >> 1;             // staging row 0..127
  const int sb = (tid & 1) << 1;      // staging slot base (16B slots): 0 or 2
  f32x4 acc[4][4] = {};

  for (int kt = 0; kt < 16; ++kt) {
    const int k0 = kt << 5;
    // stage A tile
    {
      char* dst = (char*)Al + r * 64;
      if (A_F32) {
        const float* A = (const float*)Ap + (m0 + r) * 512 + k0 + (sb << 3);
#pragma unroll
        for (int j = 0; j < 2; ++j) {
          float4 v0 = ((const float4*)A)[2 * j + 0];
          float4 v1 = ((const float4*)A)[2 * j + 1];
          short8 o;
          o[0] = (short)f2b(v0.x); o[1] = (short)f2b(v0.y);
          o[2] = (short)f2b(v0.z); o[3] = (short)f2b(v0.w);
          o[4] = (short)f2b(v1.x); o[5] = (short)f2b(v1.y);
          o[6] = (short)f2b(v1.z); o[7] = (short)f2b(v1.w);
          *(short8*)(dst + (((sb + j + (r >> 1)) & 3) << 4)) = o;
        }
      } else {
        const unsigned short* A =
            (const unsigned short*)Ap + (m0 + r) * 512 + k0 + (sb << 3);
#pragma unroll
        for (int j = 0; j < 2; ++j)
          *(short8*)(dst + (((sb + j + (r >> 1)) & 3) << 4)) =
              *(const short8*)(A + 8 * j);
      }
      // stage W tile
      const unsigned short* Wp = W + ((size_t)(n0 + r) << 9) + k0 + (sb << 3);
      char* dstB = (char*)Bl + r * 64;
#pragma unroll
      for (int j = 0; j < 2; ++j)
        *(short8*)(dstB + (((sb + j + (r >> 1)) & 3) << 4)) =
            *(const short8*)(Wp + 8 * j);
    }
    __syncthreads();
    short8 af[4], bf[4];
#pragma unroll
    for (int i = 0; i < 4; ++i) {
      int row = wr * 64 + i * 16 + lm;
      af[i] = *(const short8*)((char*)Al + row * 64 +
                               (((lq + (row >> 1)) & 3) << 4));
    }
#pragma unroll
    for (int j = 0; j < 4; ++j) {
      int row = wc * 64 + j * 16 + lm;
      bf[j] = *(const short8*)((char*)Bl + row * 64 +
                               (((lq + (row >> 1)) & 3) << 4));
    }
#pragma unroll
    for (int i = 0; i < 4; ++i)
#pragma unroll
      for (int j = 0; j < 4; ++j)
        acc[i][j] =
            __builtin_amdgcn_mfma_f32_16x16x32_bf16(af[i], bf[j], acc[i][j], 0, 0, 0);
    __syncthreads();
  }
  float bv[4];
#pragma unroll
  for (int j = 0; j < 4; ++j) bv[j] = bias[n0 + wc * 64 + j * 16 + lm];
#pragma unroll
  for (int i = 0; i < 4; ++i) {
#pragma unroll
    for (int r4 = 0; r4 < 4; ++r4) {
      size_t gm = m0 + wr * 64 + i * 16 + lq * 4 + r4;
#pragma unroll
      for (int j = 0; j < 4; ++j) {
        int gn = n0 + wc * 64 + j * 16 + lm;
        float v = acc[i][j][r4] + bv[j];
        if (OUT_BF16) {
          if (PERM) {
            // recurrence ig layout: [t][g][w][lane][j][r4]
            int b = (int)gm & 127;
            int g2 = b >> 4, mm = b & 15;
            int l2 = ((mm >> 2) << 4) | (gn & 15);
            size_t idx =
                ((((size_t)(gm >> 7) * 8 + g2) * 4 + (size_t)(gn >> 7)) * 64 +
                 l2) * 32 + (((gn >> 4) & 7) << 2) + (mm & 3);
            ((unsigned short*)Cp)[idx] = f2b(v);
          } else {
            ((unsigned short*)Cp)[(gm << 9) + gn] = f2b(v);
          }
        } else {
          ((float*)Cp)[(gm << 9) + gn] = v;
        }
      }
    }
  }
}

// ---------------- recurrence (intra-CU) ------------------------------------
// grid = 8 blocks; block g handles batches [16g,16g+16), full H=512.
// wave w owns output cols [128w,128w+128) = 8 n-tiles.
// per lane: bregs[12][8] (384 VGPR) + 4 k-chunks of B in LDS.
__global__ __launch_bounds__(256, 1) void recur2_kernel(
    const unsigned short* __restrict__ igh,  // permuted ig (aliases hs buf)
    unsigned short* __restrict__ hsw,        // hs out, normal (T*B,512) u16
    const float* __restrict__ ei2,           // permuted ei
    const unsigned short* __restrict__ wrecb,// (H,H) bf16
    const float* __restrict__ rbias,         // (H)
    float* __restrict__ h_last) {            // (B,H) f32
  __shared__ __align__(16) short8 Bls[4][4][8][64];        // 128 KB
  __shared__ __align__(16) unsigned short Als[16][512];    // 16 KB
  const int tid = threadIdx.x;
  const int g = blockIdx.x;
  const int bb = g << 4;
  const int w = tid >> 6, l = tid & 63;
  const int lm = l & 15, lq = l >> 4;
  const int nbase = w << 7;
  const int lswz = lm & 7;

  // one-time: register weights (k-chunks 0..11)
  short8 bregs[12][8];
#pragma unroll
  for (int kk = 0; kk < 12; ++kk)
#pragma unroll
    for (int j = 0; j < 8; ++j)
      bregs[kk][j] = *(const short8*)(
          wrecb + ((size_t)(nbase + j * 16 + lm) << 9) + (kk << 5) + (lq << 3));
  // one-time: LDS weights (k-chunks 12..15)
#pragma unroll
  for (int kk = 12; kk < 16; ++kk)
#pragma unroll
    for (int j = 0; j < 8; ++j)
      Bls[w][kk - 12][j][l] = *(const short8*)(
          wrecb + ((size_t)(nbase + j * 16 + lm) << 9) + (kk << 5) + (lq << 3));
  float rb[8];
#pragma unroll
  for (int j = 0; j < 8; ++j) rb[j] = rbias[nbase + j * 16 + lm];
  // zero a_lds (h0 = 0)
  {
    short8 z = {};
#pragma unroll
    for (int q = 0; q < 4; ++q) ((short8*)Als)[tid * 4 + q] = z;
  }
  __syncthreads();

#pragma unroll 1
  for (int t = 0; t < 512; ++t) {
    // prefetch ig[t] (32 bf16, contiguous 64B per lane) and ei[t+1]
    const unsigned short* igp =
        igh + ((((size_t)t * 8 + g) * 4 + w) * 64 + l) * 32;
    short8 igv[4];
    igv[0] = *(const short8*)(igp);
    igv[1] = *(const short8*)(igp + 8);
    igv[2] = *(const short8*)(igp + 16);
    igv[3] = *(const short8*)(igp + 24);
    f32x4 eif0 = {0.f, 0.f, 0.f, 0.f}, eif1 = {0.f, 0.f, 0.f, 0.f};
    if (t < 511) {
      const float* eip = ei2 + ((((size_t)(t + 1) * 4 + w) * 64 + l) << 3);
      eif0 = *(const f32x4*)(eip);
      eif1 = *(const f32x4*)(eip + 4);
    }

    f32x4 acc[8] = {};
    const char* aRow = (const char*)Als + lm * 1024;
#pragma unroll
    for (int kk = 0; kk < 12; ++kk) {
      short8 av = *(const short8*)(aRow + ((((kk << 2) | lq) ^ lswz) << 4));
#pragma unroll
      for (int j = 0; j < 8; ++j)
        acc[j] = __builtin_amdgcn_mfma_f32_16x16x32_bf16(av, bregs[kk][j],
                                                         acc[j], 0, 0, 0);
    }
#pragma unroll
    for (int kk = 12; kk < 16; ++kk) {
      short8 av = *(const short8*)(aRow + ((((kk << 2) | lq) ^ lswz) << 4));
#pragma unroll
      for (int j = 0; j < 8; ++j)
        acc[j] = __builtin_amdgcn_mfma_f32_16x16x32_bf16(av, Bls[w][kk - 12][j][l],
                                                         acc[j], 0, 0, 0);
    }
    __syncthreads();  // all waves done reading Als (and ig loads drained)

    // epilogue: h = softplus(acc + ig + rb); emit hs/h_last; a_{t+1} -> Als
#pragma unroll
    for (int j = 0; j < 8; ++j) {
      const int n = nbase + (j << 4) + lm;
      const float eiv = (j < 4) ? eif0[j] : eif1[j - 4];
#pragma unroll
      for (int r4 = 0; r4 < 4; ++r4) {
        const int mm = (lq << 2) + r4;
        float z = acc[j][r4] +
                  b2f((unsigned short)igv[j >> 1][((j & 1) << 2) + r4]) + rb[j];
        float h = (z > 20.f) ? z : log1pf(__expf(z));
        __builtin_nontemporal_store(
            f2b(h), hsw + (((size_t)(t << 7) + bb + mm) << 9) + n);
        if (t == 511) {
          h_last[((bb + mm) << 9) + n] = h;
        } else {
          unsigned short a = f2b(h * eiv);
          *(unsigned short*)((char*)Als + mm * 1024 +
                             ((((n >> 3) ^ (mm & 7)) << 4) | ((n & 7) << 1))) = a;
        }
      }
    }
    __syncthreads();  // Als writes visible before next step's K-loop
  }
}

// ---------------- launch ---------------------------------------------------
extern "C" void kernel_launch(void* const* d_in, const int* in_sizes, int n_in,
                              void* d_out, int out_size, void* d_ws,
                              size_t ws_size, hipStream_t stream) {
  const float* x     = (const float*)d_in[0];
  const float* gu    = (const float*)d_in[1];
  const float* Win   = (const float*)d_in[2];
  const float* bin   = (const float*)d_in[3];
  const float* Wrec  = (const float*)d_in[4];
  const float* rbias = (const float*)d_in[5];
  const float* elog  = (const float*)d_in[6];
  const float* Wout  = (const float*)d_in[7];
  const float* bout  = (const float*)d_in[8];

  char* ws = (char*)d_ws;
  float* ei2            = (float*)ws;                        // 4 MB
  unsigned short* wrecb = (unsigned short*)(ws + 4194304);   // 512 KB
  unsigned short* winb  = (unsigned short*)(ws + 4718592);   // 512 KB
  unsigned short* woutb = (unsigned short*)(ws + 5242880);   // 512 KB
  unsigned short* igh   = (unsigned short*)(ws + 5767168);   // 64 MB ig2/hs

  float* outp  = (float*)d_out;            // (T,B,O) f32
  float* hlast = outp + 33554432;          // (B,H)
  float* clast = outp + 33554432 + 65536;  // (B,H) zeros

  prep_kernel<<<1024, 256, 0, stream>>>(gu, elog, Wrec, Win, Wout, ei2, wrecb,
                                        winb, woutb, clast);
  gemm512<1, 1, 1><<<dim3(512, 4), 256, 0, stream>>>(x, winb, bin, igh);
  recur2_kernel<<<8, 256, 0, stream>>>(igh, igh, ei2, wrecb, rbias, hlast);
  gemm512<0, 0, 0><<<dim3(512, 4), 256, 0, stream>>>(igh, woutb, bout, outp);
}

// Round 4
// 3841.381 us; speedup vs baseline: 2.2412x; 2.2412x over previous
//
#include <hip/hip_runtime.h>
#include <stdint.h>

// EISepLSTM: x(T,B,I) -> ig GEMM -> 512-step EI recurrence -> out GEMM.
// T=512, B=128, I=H=O=512.
// Round 4: round-1 topology (32 blocks = 8 batch-groups x 4 col-chunks,
// Wrec chunk register-resident, 128 VGPR/lane). Exchange rebuilt with
// SELF-VALIDATING TAGGED WORDS: each dword = (bf16 value << 16) | step_tag,
// written/read with system-scope relaxed atomics (always coherent at MALL).
// No flags, no fences, one MALL trip per step. Parity double-buffered;
// hx memset each launch so graph replays never see stale tags.

typedef __attribute__((ext_vector_type(8))) short short8;
typedef __attribute__((ext_vector_type(4))) float f32x4;

__device__ __forceinline__ unsigned short f2b(float f) {
  unsigned int u = __float_as_uint(f);
  u = (u + 0x7fffu + ((u >> 16) & 1u)) >> 16;   // RNE
  return (unsigned short)u;
}
__device__ __forceinline__ float b2f(unsigned short s) {
  return __uint_as_float(((unsigned int)s) << 16);
}

// ---------------- prep: ei table, bf16 weight casts, c_last zeros ----------
__global__ void prep_kernel(const float* __restrict__ gu,      // (T,H,2)
                            const float* __restrict__ logit,   // (H,2)
                            const float* __restrict__ wrec,    // (H,H)
                            const float* __restrict__ win,     // (H,I)
                            const float* __restrict__ wout,    // (O,H)
                            float* __restrict__ ei,            // (T,H)
                            unsigned short* __restrict__ wrecb,
                            unsigned short* __restrict__ winb,
                            unsigned short* __restrict__ woutb,
                            float* __restrict__ c_last) {
  int i = blockIdx.x * 256 + threadIdx.x;          // 0 .. 262143
  int h = i & 511;
  float u0 = gu[2 * i], u1 = gu[2 * i + 1];
  float l0 = logit[2 * h], l1 = logit[2 * h + 1];
  float g0 = -logf(-logf(u0 + 1e-10f) + 1e-10f);
  float g1 = -logf(-logf(u1 + 1e-10f) + 1e-10f);
  // softmax2 diff == tanh(dz/2), dz = ((l0+g0)-(l1+g1))/tau
  float dz = ((l0 + g0) - (l1 + g1)) * 10.0f;
  ei[i] = tanhf(0.5f * dz);
  wrecb[i] = f2b(fmaxf(wrec[i], 0.0f));
  winb[i]  = f2b(win[i]);
  woutb[i] = f2b(wout[i]);
  if (i < 65536) c_last[i] = 0.0f;
}

// ---------------- GEMM: C[m,n] = sum_k A[m,k]*W[n,k] + bias[n] -------------
// A: M x 512 (f32 or bf16), W: 512 x 512 bf16 row-major, out f32 or bf16.
template <int A_F32, int OUT_BF16>
__global__ __launch_bounds__(256, 2) void gemm512(
    const void* __restrict__ Ap, const unsigned short* __restrict__ W,
    const float* __restrict__ bias, void* __restrict__ Cp) {
  __shared__ __align__(16) unsigned short Al[128][32];
  __shared__ __align__(16) unsigned short Bl[128][32];
  const int tid = threadIdx.x;
  const int w = tid >> 6, l = tid & 63;
  const int wr = w >> 1, wc = w & 1;
  const int lm = l & 15, lq = l >> 4;
  const size_t m0 = (size_t)blockIdx.x * 128;
  const int n0 = blockIdx.y * 128;
  const int r = tid >> 1;             // staging row 0..127
  const int sb = (tid & 1) << 1;      // staging slot base (16B slots): 0 or 2
  f32x4 acc[4][4] = {};

  for (int kt = 0; kt < 16; ++kt) {
    const int k0 = kt << 5;
    // stage A tile
    {
      char* dst = (char*)Al + r * 64;
      if (A_F32) {
        const float* A = (const float*)Ap + (m0 + r) * 512 + k0 + (sb << 3);
#pragma unroll
        for (int j = 0; j < 2; ++j) {
          float4 v0 = ((const float4*)A)[2 * j + 0];
          float4 v1 = ((const float4*)A)[2 * j + 1];
          short8 o;
          o[0] = (short)f2b(v0.x); o[1] = (short)f2b(v0.y);
          o[2] = (short)f2b(v0.z); o[3] = (short)f2b(v0.w);
          o[4] = (short)f2b(v1.x); o[5] = (short)f2b(v1.y);
          o[6] = (short)f2b(v1.z); o[7] = (short)f2b(v1.w);
          *(short8*)(dst + (((sb + j + (r >> 1)) & 3) << 4)) = o;
        }
      } else {
        const unsigned short* A =
            (const unsigned short*)Ap + (m0 + r) * 512 + k0 + (sb << 3);
#pragma unroll
        for (int j = 0; j < 2; ++j)
          *(short8*)(dst + (((sb + j + (r >> 1)) & 3) << 4)) =
              *(const short8*)(A + 8 * j);
      }
      // stage W tile
      const unsigned short* Wp = W + ((size_t)(n0 + r) << 9) + k0 + (sb << 3);
      char* dstB = (char*)Bl + r * 64;
#pragma unroll
      for (int j = 0; j < 2; ++j)
        *(short8*)(dstB + (((sb + j + (r >> 1)) & 3) << 4)) =
            *(const short8*)(Wp + 8 * j);
    }
    __syncthreads();
    short8 af[4], bf[4];
#pragma unroll
    for (int i = 0; i < 4; ++i) {
      int row = wr * 64 + i * 16 + lm;
      af[i] = *(const short8*)((char*)Al + row * 64 +
                               (((lq + (row >> 1)) & 3) << 4));
    }
#pragma unroll
    for (int j = 0; j < 4; ++j) {
      int row = wc * 64 + j * 16 + lm;
      bf[j] = *(const short8*)((char*)Bl + row * 64 +
                               (((lq + (row >> 1)) & 3) << 4));
    }
#pragma unroll
    for (int i = 0; i < 4; ++i)
#pragma unroll
      for (int j = 0; j < 4; ++j)
        acc[i][j] =
            __builtin_amdgcn_mfma_f32_16x16x32_bf16(af[i], bf[j], acc[i][j], 0, 0, 0);
    __syncthreads();
  }
  float bv[4];
#pragma unroll
  for (int j = 0; j < 4; ++j) bv[j] = bias[n0 + wc * 64 + j * 16 + lm];
#pragma unroll
  for (int i = 0; i < 4; ++i) {
#pragma unroll
    for (int r4 = 0; r4 < 4; ++r4) {
      size_t gm = m0 + wr * 64 + i * 16 + lq * 4 + r4;
#pragma unroll
      for (int j = 0; j < 4; ++j) {
        int gn = n0 + wc * 64 + j * 16 + lm;
        float v = acc[i][j][r4] + bv[j];
        if (OUT_BF16)
          ((unsigned short*)Cp)[(gm << 9) + gn] = f2b(v);
        else
          ((float*)Cp)[(gm << 9) + gn] = v;
      }
    }
  }
}

// ---------------- recurrence ----------------------------------------------
// grid = 32: g = bid&7 (batch group, 16 rows), c = bid>>3 (128-col chunk).
// Wave owns 32 cols: breg[16][2] (128 regs). a_t staged in LDS (swizzled).
// Exchange words: hxw[par][c][g][w][l][j], j = nt*4+r4,
//   word = (bf16(h*ei) << 16) | t_consume  (t_consume in 1..511).
__global__ __launch_bounds__(256, 1) void recur4_kernel(
    const unsigned short* __restrict__ ig,   // (T*B,512) bf16
    const float* __restrict__ ei,            // (T,512)
    const unsigned short* __restrict__ wrecb,// (H,H) bf16
    const float* __restrict__ rbias,         // (H)
    unsigned short* __restrict__ hs,         // (T*B,512) bf16
    unsigned int* __restrict__ hxw,          // (2,4,8,4,64,8) u32 tagged
    float* __restrict__ h_last) {            // (B,H) f32
  __shared__ __align__(16) unsigned short Als[2][16][512];   // 32 KB
  const int tid = threadIdx.x;
  const int g = blockIdx.x & 7, c = blockIdx.x >> 3;
  const int bb = g << 4;
  const int w = tid >> 6, l = tid & 63;
  const int lm = l & 15, lq = l >> 4;
  const int nb0 = (c << 7) + (w << 5);
  const int n_0 = nb0 + lm, n_1 = nb0 + 16 + lm;

  // register-resident Wrec chunk: breg[kk][nt] = Wrec[n, kk*32 + lq*8 .. +8]
  short8 breg[16][2];
#pragma unroll
  for (int kk = 0; kk < 16; ++kk) {
    breg[kk][0] = *(const short8*)(wrecb + ((size_t)n_0 << 9) + (kk << 5) + (lq << 3));
    breg[kk][1] = *(const short8*)(wrecb + ((size_t)n_1 << 9) + (kk << 5) + (lq << 3));
  }
  const float rb0 = rbias[n_0], rb1 = rbias[n_1];

#pragma unroll 1
  for (int t = 0; t < 512; ++t) {
    const int par = t & 1, par2 = par ^ 1;
    // prefetch ig[t] (round-1-proven plain layout) and ei[t+1]
    unsigned short igv[2][4];
#pragma unroll
    for (int r4 = 0; r4 < 4; ++r4) {
      size_t rowb = ((size_t)(t << 7) + bb + (lq << 2) + r4) << 9;
      igv[0][r4] = __builtin_nontemporal_load(ig + rowb + n_0);
      igv[1][r4] = __builtin_nontemporal_load(ig + rowb + n_1);
    }
    float eiv0 = 0.f, eiv1 = 0.f;
    if (t < 511) {
      eiv0 = ei[((t + 1) << 9) + n_0];
      eiv1 = ei[((t + 1) << 9) + n_1];
    }
    f32x4 acc0 = {0.f, 0.f, 0.f, 0.f}, acc1 = {0.f, 0.f, 0.f, 0.f};
    if (t > 0) {
      const unsigned int tg = (unsigned int)t;
      unsigned int rv[3][8];
      // phase 1: issue all 24 polls (pipelined)
#pragma unroll
      for (int q = 0; q < 3; ++q) {
        const int cc = (c + 1 + q) & 3;
        const unsigned int* pp =
            hxw + (((((size_t)par * 4 + cc) * 8 + g) * 4 + w) * 64 + l) * 8;
#pragma unroll
        for (int j = 0; j < 8; ++j)
          rv[q][j] = __hip_atomic_load(pp + j, __ATOMIC_RELAXED,
                                       __HIP_MEMORY_SCOPE_SYSTEM);
      }
      // phase 2: re-poll stragglers until tag == t
#pragma unroll
      for (int q = 0; q < 3; ++q) {
        const int cc = (c + 1 + q) & 3;
        const unsigned int* pp =
            hxw + (((((size_t)par * 4 + cc) * 8 + g) * 4 + w) * 64 + l) * 8;
#pragma unroll
        for (int j = 0; j < 8; ++j)
          while ((rv[q][j] & 0xffffu) != tg)
            rv[q][j] = __hip_atomic_load(pp + j, __ATOMIC_RELAXED,
                                         __HIP_MEMORY_SCOPE_SYSTEM);
      }
      // stage remote chunks into Als[par] (swizzled)
#pragma unroll
      for (int q = 0; q < 3; ++q) {
        const int cc = (c + 1 + q) & 3;
#pragma unroll
        for (int nt = 0; nt < 2; ++nt) {
          const int n = (cc << 7) + (w << 5) + (nt << 4) + lm;
#pragma unroll
          for (int r4 = 0; r4 < 4; ++r4) {
            const int mm = (lq << 2) + r4;
            *(unsigned short*)((char*)Als + par * 16384 + mm * 1024 +
                               ((((n >> 3) ^ (mm & 7)) << 4) | ((n & 7) << 1))) =
                (unsigned short)(rv[q][(nt << 2) + r4] >> 16);
          }
        }
      }
      __syncthreads();
      // K-loop: rec = a_t @ Wrec_chunk^T
      const char* aRow = (const char*)Als + par * 16384 + lm * 1024;
#pragma unroll
      for (int kk = 0; kk < 16; ++kk) {
        short8 av = *(const short8*)(aRow + ((((kk << 2) | lq) ^ (lm & 7)) << 4));
        acc0 = __builtin_amdgcn_mfma_f32_16x16x32_bf16(av, breg[kk][0], acc0, 0, 0, 0);
        acc1 = __builtin_amdgcn_mfma_f32_16x16x32_bf16(av, breg[kk][1], acc1, 0, 0, 0);
      }
    }
    // h = softplus(acc + ig + rbias)
    float hv[2][4];
#pragma unroll
    for (int nt = 0; nt < 2; ++nt) {
      const float rbv = nt ? rb1 : rb0;
#pragma unroll
      for (int r4 = 0; r4 < 4; ++r4) {
        float z = (nt ? acc1[r4] : acc0[r4]) +
                  b2f((unsigned short)igv[nt][r4]) + rbv;
        hv[nt][r4] = (z > 20.f) ? z : log1pf(__expf(z));
      }
    }
    if (t < 511) {
      // export a_{t+1} = h*ei as tagged words (critical path first)
      const unsigned int tg2 = (unsigned int)(t + 1);
      unsigned int* pp =
          hxw + (((((size_t)par2 * 4 + c) * 8 + g) * 4 + w) * 64 + l) * 8;
#pragma unroll
      for (int nt = 0; nt < 2; ++nt) {
        const float eiv = nt ? eiv1 : eiv0;
#pragma unroll
        for (int r4 = 0; r4 < 4; ++r4) {
          unsigned int word =
              ((unsigned int)f2b(hv[nt][r4] * eiv) << 16) | tg2;
          __hip_atomic_store(pp + (nt << 2) + r4, word, __ATOMIC_RELAXED,
                             __HIP_MEMORY_SCOPE_SYSTEM);
        }
      }
      // own chunk straight into next LDS buffer (swizzled)
#pragma unroll
      for (int nt = 0; nt < 2; ++nt) {
        const float eiv = nt ? eiv1 : eiv0;
        const int n = nt ? n_1 : n_0;
#pragma unroll
        for (int r4 = 0; r4 < 4; ++r4) {
          const int mm = (lq << 2) + r4;
          *(unsigned short*)((char*)Als + par2 * 16384 + mm * 1024 +
                             ((((n >> 3) ^ (mm & 7)) << 4) | ((n & 7) << 1))) =
              f2b(hv[nt][r4] * eiv);
        }
      }
    }
    // hs / h_last stores (off critical path)
#pragma unroll
    for (int nt = 0; nt < 2; ++nt) {
      const int n = nt ? n_1 : n_0;
#pragma unroll
      for (int r4 = 0; r4 < 4; ++r4) {
        const int mm = (lq << 2) + r4;
        __builtin_nontemporal_store(
            f2b(hv[nt][r4]), hs + (((size_t)(t << 7) + bb + mm) << 9) + n);
        if (t == 511) h_last[((bb + mm) << 9) + n] = hv[nt][r4];
      }
    }
  }
}

// ---------------- launch ---------------------------------------------------
extern "C" void kernel_launch(void* const* d_in, const int* in_sizes, int n_in,
                              void* d_out, int out_size, void* d_ws,
                              size_t ws_size, hipStream_t stream) {
  const float* x     = (const float*)d_in[0];
  const float* gu    = (const float*)d_in[1];
  const float* Win   = (const float*)d_in[2];
  const float* bin   = (const float*)d_in[3];
  const float* Wrec  = (const float*)d_in[4];
  const float* rbias = (const float*)d_in[5];
  const float* elog  = (const float*)d_in[6];
  const float* Wout  = (const float*)d_in[7];
  const float* bout  = (const float*)d_in[8];

  char* ws = (char*)d_ws;
  float* ei             = (float*)ws;                        // 1 MB
  unsigned short* wrecb = (unsigned short*)(ws + 1048576);   // 512 KB
  unsigned short* winb  = (unsigned short*)(ws + 1572864);   // 512 KB
  unsigned short* woutb = (unsigned short*)(ws + 2097152);   // 512 KB
  unsigned int* hxw     = (unsigned int*)(ws + 2621440);     // 512 KB
  unsigned short* ig    = (unsigned short*)(ws + 3145728);   // 64 MB
  unsigned short* hs    = (unsigned short*)(ws + 70254592);  // 64 MB

  float* outp  = (float*)d_out;            // (T,B,O) f32
  float* hlast = outp + 33554432;          // (B,H)
  float* clast = outp + 33554432 + 65536;  // (B,H) zeros

  hipMemsetAsync(hxw, 0, 524288, stream);  // clear tags (graph-replay safe)
  prep_kernel<<<1024, 256, 0, stream>>>(gu, elog, Wrec, Win, Wout, ei, wrecb,
                                        winb, woutb, clast);
  gemm512<1, 1><<<dim3(512, 4), 256, 0, stream>>>(x, winb, bin, ig);
  recur4_kernel<<<32, 256, 0, stream>>>(ig, ei, wrecb, rbias, hs, hxw, hlast);
  gemm512<0, 0><<<dim3(512, 4), 256, 0, stream>>>(hs, woutb, bout, outp);
}

// Round 5
// 2742.294 us; speedup vs baseline: 3.1395x; 1.4008x over previous
//
#include <hip/hip_runtime.h>
#include <stdint.h>

// EISepLSTM: x(T,B,I) -> ig GEMM -> 512-step EI recurrence -> out GEMM.
// T=512, B=128, I=H=O=512.
// Round 5: round-4 tagged-word exchange (self-validating dwords, system-scope
// atomics, parity double-buffer) with BATCHED SWEEP POLLING: all 24 remote
// words reloaded per sweep as 12 independent u64 atomic loads -> one memory
// latency per sweep instead of 24 serialized dependent spin loops.

typedef __attribute__((ext_vector_type(8))) short short8;
typedef __attribute__((ext_vector_type(4))) float f32x4;

__device__ __forceinline__ unsigned short f2b(float f) {
  unsigned int u = __float_as_uint(f);
  u = (u + 0x7fffu + ((u >> 16) & 1u)) >> 16;   // RNE
  return (unsigned short)u;
}
__device__ __forceinline__ float b2f(unsigned short s) {
  return __uint_as_float(((unsigned int)s) << 16);
}

// ---------------- prep: ei table, bf16 weight casts, c_last zeros ----------
__global__ void prep_kernel(const float* __restrict__ gu,      // (T,H,2)
                            const float* __restrict__ logit,   // (H,2)
                            const float* __restrict__ wrec,    // (H,H)
                            const float* __restrict__ win,     // (H,I)
                            const float* __restrict__ wout,    // (O,H)
                            float* __restrict__ ei,            // (T,H)
                            unsigned short* __restrict__ wrecb,
                            unsigned short* __restrict__ winb,
                            unsigned short* __restrict__ woutb,
                            float* __restrict__ c_last) {
  int i = blockIdx.x * 256 + threadIdx.x;          // 0 .. 262143
  int h = i & 511;
  float u0 = gu[2 * i], u1 = gu[2 * i + 1];
  float l0 = logit[2 * h], l1 = logit[2 * h + 1];
  float g0 = -logf(-logf(u0 + 1e-10f) + 1e-10f);
  float g1 = -logf(-logf(u1 + 1e-10f) + 1e-10f);
  // softmax2 diff == tanh(dz/2), dz = ((l0+g0)-(l1+g1))/tau
  float dz = ((l0 + g0) - (l1 + g1)) * 10.0f;
  ei[i] = tanhf(0.5f * dz);
  wrecb[i] = f2b(fmaxf(wrec[i], 0.0f));
  winb[i]  = f2b(win[i]);
  woutb[i] = f2b(wout[i]);
  if (i < 65536) c_last[i] = 0.0f;
}

// ---------------- GEMM: C[m,n] = sum_k A[m,k]*W[n,k] + bias[n] -------------
// A: M x 512 (f32 or bf16), W: 512 x 512 bf16 row-major, out f32 or bf16.
template <int A_F32, int OUT_BF16>
__global__ __launch_bounds__(256, 2) void gemm512(
    const void* __restrict__ Ap, const unsigned short* __restrict__ W,
    const float* __restrict__ bias, void* __restrict__ Cp) {
  __shared__ __align__(16) unsigned short Al[128][32];
  __shared__ __align__(16) unsigned short Bl[128][32];
  const int tid = threadIdx.x;
  const int w = tid >> 6, l = tid & 63;
  const int wr = w >> 1, wc = w & 1;
  const int lm = l & 15, lq = l >> 4;
  const size_t m0 = (size_t)blockIdx.x * 128;
  const int n0 = blockIdx.y * 128;
  const int r = tid >> 1;             // staging row 0..127
  const int sb = (tid & 1) << 1;      // staging slot base (16B slots): 0 or 2
  f32x4 acc[4][4] = {};

  for (int kt = 0; kt < 16; ++kt) {
    const int k0 = kt << 5;
    // stage A tile
    {
      char* dst = (char*)Al + r * 64;
      if (A_F32) {
        const float* A = (const float*)Ap + (m0 + r) * 512 + k0 + (sb << 3);
#pragma unroll
        for (int j = 0; j < 2; ++j) {
          float4 v0 = ((const float4*)A)[2 * j + 0];
          float4 v1 = ((const float4*)A)[2 * j + 1];
          short8 o;
          o[0] = (short)f2b(v0.x); o[1] = (short)f2b(v0.y);
          o[2] = (short)f2b(v0.z); o[3] = (short)f2b(v0.w);
          o[4] = (short)f2b(v1.x); o[5] = (short)f2b(v1.y);
          o[6] = (short)f2b(v1.z); o[7] = (short)f2b(v1.w);
          *(short8*)(dst + (((sb + j + (r >> 1)) & 3) << 4)) = o;
        }
      } else {
        const unsigned short* A =
            (const unsigned short*)Ap + (m0 + r) * 512 + k0 + (sb << 3);
#pragma unroll
        for (int j = 0; j < 2; ++j)
          *(short8*)(dst + (((sb + j + (r >> 1)) & 3) << 4)) =
              *(const short8*)(A + 8 * j);
      }
      // stage W tile
      const unsigned short* Wp = W + ((size_t)(n0 + r) << 9) + k0 + (sb << 3);
      char* dstB = (char*)Bl + r * 64;
#pragma unroll
      for (int j = 0; j < 2; ++j)
        *(short8*)(dstB + (((sb + j + (r >> 1)) & 3) << 4)) =
            *(const short8*)(Wp + 8 * j);
    }
    __syncthreads();
    short8 af[4], bf[4];
#pragma unroll
    for (int i = 0; i < 4; ++i) {
      int row = wr * 64 + i * 16 + lm;
      af[i] = *(const short8*)((char*)Al + row * 64 +
                               (((lq + (row >> 1)) & 3) << 4));
    }
#pragma unroll
    for (int j = 0; j < 4; ++j) {
      int row = wc * 64 + j * 16 + lm;
      bf[j] = *(const short8*)((char*)Bl + row * 64 +
                               (((lq + (row >> 1)) & 3) << 4));
    }
#pragma unroll
    for (int i = 0; i < 4; ++i)
#pragma unroll
      for (int j = 0; j < 4; ++j)
        acc[i][j] =
            __builtin_amdgcn_mfma_f32_16x16x32_bf16(af[i], bf[j], acc[i][j], 0, 0, 0);
    __syncthreads();
  }
  float bv[4];
#pragma unroll
  for (int j = 0; j < 4; ++j) bv[j] = bias[n0 + wc * 64 + j * 16 + lm];
#pragma unroll
  for (int i = 0; i < 4; ++i) {
#pragma unroll
    for (int r4 = 0; r4 < 4; ++r4) {
      size_t gm = m0 + wr * 64 + i * 16 + lq * 4 + r4;
#pragma unroll
      for (int j = 0; j < 4; ++j) {
        int gn = n0 + wc * 64 + j * 16 + lm;
        float v = acc[i][j][r4] + bv[j];
        if (OUT_BF16)
          ((unsigned short*)Cp)[(gm << 9) + gn] = f2b(v);
        else
          ((float*)Cp)[(gm << 9) + gn] = v;
      }
    }
  }
}

// ---------------- recurrence ----------------------------------------------
// grid = 32: g = bid&7 (batch group, 16 rows), c = bid>>3 (128-col chunk).
// Wave owns 32 cols: breg[16][2] (128 regs). a_t staged in LDS (swizzled).
// Exchange words (u32 view): hxw[par][c][g][w][l][jj], jj = nt*4+r4,
//   word = (bf16(h*ei) << 16) | t_consume. Polled as u64 pairs, batched.
__global__ __launch_bounds__(256, 1) void recur5_kernel(
    const unsigned short* __restrict__ ig,   // (T*B,512) bf16
    const float* __restrict__ ei,            // (T,512)
    const unsigned short* __restrict__ wrecb,// (H,H) bf16
    const float* __restrict__ rbias,         // (H)
    unsigned short* __restrict__ hs,         // (T*B,512) bf16
    unsigned long long* __restrict__ hx64,   // (2,4,8,4,64,4) u64 tagged
    float* __restrict__ h_last) {            // (B,H) f32
  __shared__ __align__(16) unsigned short Als[2][16][512];   // 32 KB
  const int tid = threadIdx.x;
  const int g = blockIdx.x & 7, c = blockIdx.x >> 3;
  const int bb = g << 4;
  const int w = tid >> 6, l = tid & 63;
  const int lm = l & 15, lq = l >> 4;
  const int nb0 = (c << 7) + (w << 5);
  const int n_0 = nb0 + lm, n_1 = nb0 + 16 + lm;

  // register-resident Wrec chunk: breg[kk][nt] = Wrec[n, kk*32 + lq*8 .. +8]
  short8 breg[16][2];
#pragma unroll
  for (int kk = 0; kk < 16; ++kk) {
    breg[kk][0] = *(const short8*)(wrecb + ((size_t)n_0 << 9) + (kk << 5) + (lq << 3));
    breg[kk][1] = *(const short8*)(wrecb + ((size_t)n_1 << 9) + (kk << 5) + (lq << 3));
  }
  const float rb0 = rbias[n_0], rb1 = rbias[n_1];

#pragma unroll 1
  for (int t = 0; t < 512; ++t) {
    const int par = t & 1, par2 = par ^ 1;
    // prefetch ig[t] and ei[t+1] (latency hides under the poll sweeps)
    unsigned short igv[2][4];
#pragma unroll
    for (int r4 = 0; r4 < 4; ++r4) {
      size_t rowb = ((size_t)(t << 7) + bb + (lq << 2) + r4) << 9;
      igv[0][r4] = __builtin_nontemporal_load(ig + rowb + n_0);
      igv[1][r4] = __builtin_nontemporal_load(ig + rowb + n_1);
    }
    float eiv0 = 0.f, eiv1 = 0.f;
    if (t < 511) {
      eiv0 = ei[((t + 1) << 9) + n_0];
      eiv1 = ei[((t + 1) << 9) + n_1];
    }
    f32x4 acc0 = {0.f, 0.f, 0.f, 0.f}, acc1 = {0.f, 0.f, 0.f, 0.f};
    if (t > 0) {
      const unsigned long long tgx =
          (unsigned long long)t | ((unsigned long long)t << 32);
      unsigned long long rv[3][4];
      // batched sweep: 12 independent u64 loads per sweep, then check tags
#pragma unroll 1
      for (;;) {
        bool ok = true;
#pragma unroll
        for (int q = 0; q < 3; ++q) {
          const int cc = (c + 1 + q) & 3;
          const unsigned long long* pp =
              hx64 + (((((size_t)par * 4 + cc) * 8 + g) * 4 + w) * 64 + l) * 4;
#pragma unroll
          for (int j = 0; j < 4; ++j) {
            rv[q][j] = __hip_atomic_load(pp + j, __ATOMIC_RELAXED,
                                         __HIP_MEMORY_SCOPE_SYSTEM);
            ok &= (((rv[q][j] ^ tgx) & 0x0000ffff0000ffffULL) == 0);
          }
        }
        if (ok) break;
      }
      // stage remote chunks into Als[par] (swizzled)
#pragma unroll
      for (int q = 0; q < 3; ++q) {
        const int cc = (c + 1 + q) & 3;
#pragma unroll
        for (int nt = 0; nt < 2; ++nt) {
          const int n = (cc << 7) + (w << 5) + (nt << 4) + lm;
#pragma unroll
          for (int r4 = 0; r4 < 4; ++r4) {
            const int jj = (nt << 2) + r4;
            const unsigned short v =
                (jj & 1) ? (unsigned short)(rv[q][jj >> 1] >> 48)
                         : (unsigned short)(rv[q][jj >> 1] >> 16);
            const int mm = (lq << 2) + r4;
            *(unsigned short*)((char*)Als + par * 16384 + mm * 1024 +
                               ((((n >> 3) ^ (mm & 7)) << 4) | ((n & 7) << 1))) = v;
          }
        }
      }
      __syncthreads();
      // K-loop: rec = a_t @ Wrec_chunk^T
      const char* aRow = (const char*)Als + par * 16384 + lm * 1024;
#pragma unroll
      for (int kk = 0; kk < 16; ++kk) {
        short8 av = *(const short8*)(aRow + ((((kk << 2) | lq) ^ (lm & 7)) << 4));
        acc0 = __builtin_amdgcn_mfma_f32_16x16x32_bf16(av, breg[kk][0], acc0, 0, 0, 0);
        acc1 = __builtin_amdgcn_mfma_f32_16x16x32_bf16(av, breg[kk][1], acc1, 0, 0, 0);
      }
    }
    // h = softplus(acc + ig + rbias)
    float hv[2][4];
#pragma unroll
    for (int nt = 0; nt < 2; ++nt) {
      const float rbv = nt ? rb1 : rb0;
#pragma unroll
      for (int r4 = 0; r4 < 4; ++r4) {
        float z = (nt ? acc1[r4] : acc0[r4]) +
                  b2f((unsigned short)igv[nt][r4]) + rbv;
        hv[nt][r4] = (z > 20.f) ? z : log1pf(__expf(z));
      }
    }
    if (t < 511) {
      // export a_{t+1} = h*ei as tagged u64 words (critical path first)
      const unsigned int tg2 = (unsigned int)(t + 1);
      unsigned long long* pp =
          hx64 + (((((size_t)par2 * 4 + c) * 8 + g) * 4 + w) * 64 + l) * 4;
#pragma unroll
      for (int nt = 0; nt < 2; ++nt) {
        const float eiv = nt ? eiv1 : eiv0;
#pragma unroll
        for (int r2 = 0; r2 < 2; ++r2) {
          unsigned int w0 =
              ((unsigned int)f2b(hv[nt][2 * r2 + 0] * eiv) << 16) | tg2;
          unsigned int w1 =
              ((unsigned int)f2b(hv[nt][2 * r2 + 1] * eiv) << 16) | tg2;
          unsigned long long word =
              (unsigned long long)w0 | ((unsigned long long)w1 << 32);
          __hip_atomic_store(pp + (nt << 1) + r2, word, __ATOMIC_RELAXED,
                             __HIP_MEMORY_SCOPE_SYSTEM);
        }
      }
      // own chunk straight into next LDS buffer (swizzled)
#pragma unroll
      for (int nt = 0; nt < 2; ++nt) {
        const float eiv = nt ? eiv1 : eiv0;
        const int n = nt ? n_1 : n_0;
#pragma unroll
        for (int r4 = 0; r4 < 4; ++r4) {
          const int mm = (lq << 2) + r4;
          *(unsigned short*)((char*)Als + par2 * 16384 + mm * 1024 +
                             ((((n >> 3) ^ (mm & 7)) << 4) | ((n & 7) << 1))) =
              f2b(hv[nt][r4] * eiv);
        }
      }
    }
    // hs / h_last stores (off critical path)
#pragma unroll
    for (int nt = 0; nt < 2; ++nt) {
      const int n = nt ? n_1 : n_0;
#pragma unroll
      for (int r4 = 0; r4 < 4; ++r4) {
        const int mm = (lq << 2) + r4;
        __builtin_nontemporal_store(
            f2b(hv[nt][r4]), hs + (((size_t)(t << 7) + bb + mm) << 9) + n);
        if (t == 511) h_last[((bb + mm) << 9) + n] = hv[nt][r4];
      }
    }
  }
}

// ---------------- launch ---------------------------------------------------
extern "C" void kernel_launch(void* const* d_in, const int* in_sizes, int n_in,
                              void* d_out, int out_size, void* d_ws,
                              size_t ws_size, hipStream_t stream) {
  const float* x     = (const float*)d_in[0];
  const float* gu    = (const float*)d_in[1];
  const float* Win   = (const float*)d_in[2];
  const float* bin   = (const float*)d_in[3];
  const float* Wrec  = (const float*)d_in[4];
  const float* rbias = (const float*)d_in[5];
  const float* elog  = (const float*)d_in[6];
  const float* Wout  = (const float*)d_in[7];
  const float* bout  = (const float*)d_in[8];

  char* ws = (char*)d_ws;
  float* ei             = (float*)ws;                        // 1 MB
  unsigned short* wrecb = (unsigned short*)(ws + 1048576);   // 512 KB
  unsigned short* winb  = (unsigned short*)(ws + 1572864);   // 512 KB
  unsigned short* woutb = (unsigned short*)(ws + 2097152);   // 512 KB
  unsigned long long* hx64 = (unsigned long long*)(ws + 2621440);  // 512 KB
  unsigned short* ig    = (unsigned short*)(ws + 3145728);   // 64 MB
  unsigned short* hs    = (unsigned short*)(ws + 70254592);  // 64 MB

  float* outp  = (float*)d_out;            // (T,B,O) f32
  float* hlast = outp + 33554432;          // (B,H)
  float* clast = outp + 33554432 + 65536;  // (B,H) zeros

  hipMemsetAsync(hx64, 0, 524288, stream);  // clear tags (graph-replay safe)
  prep_kernel<<<1024, 256, 0, stream>>>(gu, elog, Wrec, Win, Wout, ei, wrecb,
                                        winb, woutb, clast);
  gemm512<1, 1><<<dim3(512, 4), 256, 0, stream>>>(x, winb, bin, ig);
  recur5_kernel<<<32, 256, 0, stream>>>(ig, ei, wrecb, rbias, hs, hx64, hlast);
  gemm512<0, 0><<<dim3(512, 4), 256, 0, stream>>>(hs, woutb, bout, outp);
}

// Round 6
// 2365.904 us; speedup vs baseline: 3.6390x; 1.1591x over previous
//
#include <hip/hip_runtime.h>
#include <stdint.h>

// EISepLSTM: x(T,B,I) -> ig GEMM -> 512-step EI recurrence -> out GEMM.
// T=512, B=128, I=H=O=512.
// Round 6: round-5 tagged-word exchange, but the poll sweep is TRULY batched:
// phase 1 issues all 12 u64 system-scope loads (no consumers in between,
// sched_barrier after), phase 2 checks tags. One memory latency per sweep
// instead of 12 serialized waits (round 5's hidden bug).

typedef __attribute__((ext_vector_type(8))) short short8;
typedef __attribute__((ext_vector_type(4))) float f32x4;

__device__ __forceinline__ unsigned short f2b(float f) {
  unsigned int u = __float_as_uint(f);
  u = (u + 0x7fffu + ((u >> 16) & 1u)) >> 16;   // RNE
  return (unsigned short)u;
}
__device__ __forceinline__ float b2f(unsigned short s) {
  return __uint_as_float(((unsigned int)s) << 16);
}

// ---------------- prep: ei table, bf16 weight casts, c_last zeros ----------
__global__ void prep_kernel(const float* __restrict__ gu,      // (T,H,2)
                            const float* __restrict__ logit,   // (H,2)
                            const float* __restrict__ wrec,    // (H,H)
                            const float* __restrict__ win,     // (H,I)
                            const float* __restrict__ wout,    // (O,H)
                            float* __restrict__ ei,            // (T,H)
                            unsigned short* __restrict__ wrecb,
                            unsigned short* __restrict__ winb,
                            unsigned short* __restrict__ woutb,
                            float* __restrict__ c_last) {
  int i = blockIdx.x * 256 + threadIdx.x;          // 0 .. 262143
  int h = i & 511;
  float u0 = gu[2 * i], u1 = gu[2 * i + 1];
  float l0 = logit[2 * h], l1 = logit[2 * h + 1];
  float g0 = -logf(-logf(u0 + 1e-10f) + 1e-10f);
  float g1 = -logf(-logf(u1 + 1e-10f) + 1e-10f);
  // softmax2 diff == tanh(dz/2), dz = ((l0+g0)-(l1+g1))/tau
  float dz = ((l0 + g0) - (l1 + g1)) * 10.0f;
  ei[i] = tanhf(0.5f * dz);
  wrecb[i] = f2b(fmaxf(wrec[i], 0.0f));
  winb[i]  = f2b(win[i]);
  woutb[i] = f2b(wout[i]);
  if (i < 65536) c_last[i] = 0.0f;
}

// ---------------- GEMM: C[m,n] = sum_k A[m,k]*W[n,k] + bias[n] -------------
// A: M x 512 (f32 or bf16), W: 512 x 512 bf16 row-major, out f32 or bf16.
template <int A_F32, int OUT_BF16>
__global__ __launch_bounds__(256, 2) void gemm512(
    const void* __restrict__ Ap, const unsigned short* __restrict__ W,
    const float* __restrict__ bias, void* __restrict__ Cp) {
  __shared__ __align__(16) unsigned short Al[128][32];
  __shared__ __align__(16) unsigned short Bl[128][32];
  const int tid = threadIdx.x;
  const int w = tid >> 6, l = tid & 63;
  const int wr = w >> 1, wc = w & 1;
  const int lm = l & 15, lq = l >> 4;
  const size_t m0 = (size_t)blockIdx.x * 128;
  const int n0 = blockIdx.y * 128;
  const int r = tid >> 1;             // staging row 0..127
  const int sb = (tid & 1) << 1;      // staging slot base (16B slots): 0 or 2
  f32x4 acc[4][4] = {};

  for (int kt = 0; kt < 16; ++kt) {
    const int k0 = kt << 5;
    // stage A tile
    {
      char* dst = (char*)Al + r * 64;
      if (A_F32) {
        const float* A = (const float*)Ap + (m0 + r) * 512 + k0 + (sb << 3);
#pragma unroll
        for (int j = 0; j < 2; ++j) {
          float4 v0 = ((const float4*)A)[2 * j + 0];
          float4 v1 = ((const float4*)A)[2 * j + 1];
          short8 o;
          o[0] = (short)f2b(v0.x); o[1] = (short)f2b(v0.y);
          o[2] = (short)f2b(v0.z); o[3] = (short)f2b(v0.w);
          o[4] = (short)f2b(v1.x); o[5] = (short)f2b(v1.y);
          o[6] = (short)f2b(v1.z); o[7] = (short)f2b(v1.w);
          *(short8*)(dst + (((sb + j + (r >> 1)) & 3) << 4)) = o;
        }
      } else {
        const unsigned short* A =
            (const unsigned short*)Ap + (m0 + r) * 512 + k0 + (sb << 3);
#pragma unroll
        for (int j = 0; j < 2; ++j)
          *(short8*)(dst + (((sb + j + (r >> 1)) & 3) << 4)) =
              *(const short8*)(A + 8 * j);
      }
      // stage W tile
      const unsigned short* Wp = W + ((size_t)(n0 + r) << 9) + k0 + (sb << 3);
      char* dstB = (char*)Bl + r * 64;
#pragma unroll
      for (int j = 0; j < 2; ++j)
        *(short8*)(dstB + (((sb + j + (r >> 1)) & 3) << 4)) =
            *(const short8*)(Wp + 8 * j);
    }
    __syncthreads();
    short8 af[4], bf[4];
#pragma unroll
    for (int i = 0; i < 4; ++i) {
      int row = wr * 64 + i * 16 + lm;
      af[i] = *(const short8*)((char*)Al + row * 64 +
                               (((lq + (row >> 1)) & 3) << 4));
    }
#pragma unroll
    for (int j = 0; j < 4; ++j) {
      int row = wc * 64 + j * 16 + lm;
      bf[j] = *(const short8*)((char*)Bl + row * 64 +
                               (((lq + (row >> 1)) & 3) << 4));
    }
#pragma unroll
    for (int i = 0; i < 4; ++i)
#pragma unroll
      for (int j = 0; j < 4; ++j)
        acc[i][j] =
            __builtin_amdgcn_mfma_f32_16x16x32_bf16(af[i], bf[j], acc[i][j], 0, 0, 0);
    __syncthreads();
  }
  float bv[4];
#pragma unroll
  for (int j = 0; j < 4; ++j) bv[j] = bias[n0 + wc * 64 + j * 16 + lm];
#pragma unroll
  for (int i = 0; i < 4; ++i) {
#pragma unroll
    for (int r4 = 0; r4 < 4; ++r4) {
      size_t gm = m0 + wr * 64 + i * 16 + lq * 4 + r4;
#pragma unroll
      for (int j = 0; j < 4; ++j) {
        int gn = n0 + wc * 64 + j * 16 + lm;
        float v = acc[i][j][r4] + bv[j];
        if (OUT_BF16)
          ((unsigned short*)Cp)[(gm << 9) + gn] = f2b(v);
        else
          ((float*)Cp)[(gm << 9) + gn] = v;
      }
    }
  }
}

// ---------------- recurrence ----------------------------------------------
// grid = 32: g = bid&7 (batch group, 16 rows), c = bid>>3 (128-col chunk).
// Wave owns 32 cols: breg[16][2] (128 regs). a_t staged in LDS (swizzled).
// Exchange words (u32 view): hxw[par][c][g][w][l][jj], jj = nt*4+r4,
//   word = (bf16(h*ei) << 16) | t_consume. Polled as u64 pairs, batched.
__global__ __launch_bounds__(256, 1) void recur6_kernel(
    const unsigned short* __restrict__ ig,   // (T*B,512) bf16
    const float* __restrict__ ei,            // (T,512)
    const unsigned short* __restrict__ wrecb,// (H,H) bf16
    const float* __restrict__ rbias,         // (H)
    unsigned short* __restrict__ hs,         // (T*B,512) bf16
    unsigned long long* __restrict__ hx64,   // (2,4,8,4,64,4) u64 tagged
    float* __restrict__ h_last) {            // (B,H) f32
  __shared__ __align__(16) unsigned short Als[2][16][512];   // 32 KB
  const int tid = threadIdx.x;
  const int g = blockIdx.x & 7, c = blockIdx.x >> 3;
  const int bb = g << 4;
  const int w = tid >> 6, l = tid & 63;
  const int lm = l & 15, lq = l >> 4;
  const int nb0 = (c << 7) + (w << 5);
  const int n_0 = nb0 + lm, n_1 = nb0 + 16 + lm;

  // register-resident Wrec chunk: breg[kk][nt] = Wrec[n, kk*32 + lq*8 .. +8]
  short8 breg[16][2];
#pragma unroll
  for (int kk = 0; kk < 16; ++kk) {
    breg[kk][0] = *(const short8*)(wrecb + ((size_t)n_0 << 9) + (kk << 5) + (lq << 3));
    breg[kk][1] = *(const short8*)(wrecb + ((size_t)n_1 << 9) + (kk << 5) + (lq << 3));
  }
  const float rb0 = rbias[n_0], rb1 = rbias[n_1];

  // precompute the 3 remote poll base pointers (loop-invariant)
  const unsigned long long* ppq[3];
#pragma unroll
  for (int q = 0; q < 3; ++q) {
    const int cc = (c + 1 + q) & 3;
    ppq[q] = hx64 + ((((size_t)cc * 8 + g) * 4 + w) * 64 + l) * 4;
  }
  const size_t parOff = (size_t)4 * 8 * 4 * 64 * 4;   // u64s per parity buf

#pragma unroll 1
  for (int t = 0; t < 512; ++t) {
    const int par = t & 1, par2 = par ^ 1;
    // prefetch ig[t] and ei[t+1] (latency hides under the poll sweeps)
    unsigned short igv[2][4];
#pragma unroll
    for (int r4 = 0; r4 < 4; ++r4) {
      size_t rowb = ((size_t)(t << 7) + bb + (lq << 2) + r4) << 9;
      igv[0][r4] = __builtin_nontemporal_load(ig + rowb + n_0);
      igv[1][r4] = __builtin_nontemporal_load(ig + rowb + n_1);
    }
    float eiv0 = 0.f, eiv1 = 0.f;
    if (t < 511) {
      eiv0 = ei[((t + 1) << 9) + n_0];
      eiv1 = ei[((t + 1) << 9) + n_1];
    }
    f32x4 acc0 = {0.f, 0.f, 0.f, 0.f}, acc1 = {0.f, 0.f, 0.f, 0.f};
    if (t > 0) {
      const unsigned long long tgx =
          (unsigned long long)t | ((unsigned long long)t << 32);
      unsigned long long rv[3][4];
      // batched sweep: phase 1 = issue all 12 u64 loads (NO consumers),
      // phase 2 = check tags. One memory latency per sweep.
#pragma unroll 1
      for (;;) {
#pragma unroll
        for (int q = 0; q < 3; ++q) {
          const unsigned long long* pp = ppq[q] + (par ? parOff : 0);
#pragma unroll
          for (int j = 0; j < 4; ++j)
            rv[q][j] = __hip_atomic_load(pp + j, __ATOMIC_RELAXED,
                                         __HIP_MEMORY_SCOPE_SYSTEM);
        }
        __builtin_amdgcn_sched_barrier(0);   // keep checks after all issues
        bool ok = true;
#pragma unroll
        for (int q = 0; q < 3; ++q)
#pragma unroll
          for (int j = 0; j < 4; ++j)
            ok &= (((rv[q][j] ^ tgx) & 0x0000ffff0000ffffULL) == 0);
        if (ok) break;
      }
      // stage remote chunks into Als[par] (swizzled)
#pragma unroll
      for (int q = 0; q < 3; ++q) {
        const int cc = (c + 1 + q) & 3;
#pragma unroll
        for (int nt = 0; nt < 2; ++nt) {
          const int n = (cc << 7) + (w << 5) + (nt << 4) + lm;
#pragma unroll
          for (int r4 = 0; r4 < 4; ++r4) {
            const int jj = (nt << 2) + r4;
            const unsigned short v =
                (jj & 1) ? (unsigned short)(rv[q][jj >> 1] >> 48)
                         : (unsigned short)(rv[q][jj >> 1] >> 16);
            const int mm = (lq << 2) + r4;
            *(unsigned short*)((char*)Als + par * 16384 + mm * 1024 +
                               ((((n >> 3) ^ (mm & 7)) << 4) | ((n & 7) << 1))) = v;
          }
        }
      }
      __syncthreads();
      // K-loop: rec = a_t @ Wrec_chunk^T
      const char* aRow = (const char*)Als + par * 16384 + lm * 1024;
#pragma unroll
      for (int kk = 0; kk < 16; ++kk) {
        short8 av = *(const short8*)(aRow + ((((kk << 2) | lq) ^ (lm & 7)) << 4));
        acc0 = __builtin_amdgcn_mfma_f32_16x16x32_bf16(av, breg[kk][0], acc0, 0, 0, 0);
        acc1 = __builtin_amdgcn_mfma_f32_16x16x32_bf16(av, breg[kk][1], acc1, 0, 0, 0);
      }
    }
    // h = softplus(acc + ig + rbias)
    float hv[2][4];
#pragma unroll
    for (int nt = 0; nt < 2; ++nt) {
      const float rbv = nt ? rb1 : rb0;
#pragma unroll
      for (int r4 = 0; r4 < 4; ++r4) {
        float z = (nt ? acc1[r4] : acc0[r4]) +
                  b2f((unsigned short)igv[nt][r4]) + rbv;
        hv[nt][r4] = (z > 20.f) ? z : log1pf(__expf(z));
      }
    }
    if (t < 511) {
      // export a_{t+1} = h*ei as tagged u64 words (critical path first)
      const unsigned int tg2 = (unsigned int)(t + 1);
      unsigned long long* pp =
          hx64 + (((((size_t)par2 * 4 + c) * 8 + g) * 4 + w) * 64 + l) * 4;
#pragma unroll
      for (int nt = 0; nt < 2; ++nt) {
        const float eiv = nt ? eiv1 : eiv0;
#pragma unroll
        for (int r2 = 0; r2 < 2; ++r2) {
          unsigned int w0 =
              ((unsigned int)f2b(hv[nt][2 * r2 + 0] * eiv) << 16) | tg2;
          unsigned int w1 =
              ((unsigned int)f2b(hv[nt][2 * r2 + 1] * eiv) << 16) | tg2;
          unsigned long long word =
              (unsigned long long)w0 | ((unsigned long long)w1 << 32);
          __hip_atomic_store(pp + (nt << 1) + r2, word, __ATOMIC_RELAXED,
                             __HIP_MEMORY_SCOPE_SYSTEM);
        }
      }
      // own chunk straight into next LDS buffer (swizzled)
#pragma unroll
      for (int nt = 0; nt < 2; ++nt) {
        const float eiv = nt ? eiv1 : eiv0;
        const int n = nt ? n_1 : n_0;
#pragma unroll
        for (int r4 = 0; r4 < 4; ++r4) {
          const int mm = (lq << 2) + r4;
          *(unsigned short*)((char*)Als + par2 * 16384 + mm * 1024 +
                             ((((n >> 3) ^ (mm & 7)) << 4) | ((n & 7) << 1))) =
              f2b(hv[nt][r4] * eiv);
        }
      }
    }
    // hs / h_last stores (off critical path)
#pragma unroll
    for (int nt = 0; nt < 2; ++nt) {
      const int n = nt ? n_1 : n_0;
#pragma unroll
      for (int r4 = 0; r4 < 4; ++r4) {
        const int mm = (lq << 2) + r4;
        __builtin_nontemporal_store(
            f2b(hv[nt][r4]), hs + (((size_t)(t << 7) + bb + mm) << 9) + n);
        if (t == 511) h_last[((bb + mm) << 9) + n] = hv[nt][r4];
      }
    }
  }
}

// ---------------- launch ---------------------------------------------------
extern "C" void kernel_launch(void* const* d_in, const int* in_sizes, int n_in,
                              void* d_out, int out_size, void* d_ws,
                              size_t ws_size, hipStream_t stream) {
  const float* x     = (const float*)d_in[0];
  const float* gu    = (const float*)d_in[1];
  const float* Win   = (const float*)d_in[2];
  const float* bin   = (const float*)d_in[3];
  const float* Wrec  = (const float*)d_in[4];
  const float* rbias = (const float*)d_in[5];
  const float* elog  = (const float*)d_in[6];
  const float* Wout  = (const float*)d_in[7];
  const float* bout  = (const float*)d_in[8];

  char* ws = (char*)d_ws;
  float* ei             = (float*)ws;                        // 1 MB
  unsigned short* wrecb = (unsigned short*)(ws + 1048576);   // 512 KB
  unsigned short* winb  = (unsigned short*)(ws + 1572864);   // 512 KB
  unsigned short* woutb = (unsigned short*)(ws + 2097152);   // 512 KB
  unsigned long long* hx64 = (unsigned long long*)(ws + 2621440);  // 512 KB
  unsigned short* ig    = (unsigned short*)(ws + 3145728);   // 64 MB
  unsigned short* hs    = (unsigned short*)(ws + 70254592);  // 64 MB

  float* outp  = (float*)d_out;            // (T,B,O) f32
  float* hlast = outp + 33554432;          // (B,H)
  float* clast = outp + 33554432 + 65536;  // (B,H) zeros

  hipMemsetAsync(hx64, 0, 524288, stream);  // clear tags (graph-replay safe)
  prep_kernel<<<1024, 256, 0, stream>>>(gu, elog, Wrec, Win, Wout, ei, wrecb,
                                        winb, woutb, clast);
  gemm512<1, 1><<<dim3(512, 4), 256, 0, stream>>>(x, winb, bin, ig);
  recur6_kernel<<<32, 256, 0, stream>>>(ig, ei, wrecb, rbias, hs, hx64, hlast);
  gemm512<0, 0><<<dim3(512, 4), 256, 0, stream>>>(hs, woutb, bout, outp);
}